// Round 6
// baseline (323.393 us; speedup 1.0000x reference)
//
#include <hip/hip_runtime.h>

#define BB 4
#define CCH 256
#define NPIX 4096
#define EPS 1e-6f

typedef __attribute__((ext_vector_type(8))) short bf16x8;
typedef __attribute__((ext_vector_type(4))) float f32x4;
typedef __attribute__((ext_vector_type(16))) float f32x16;

__device__ __forceinline__ unsigned short f2bf(float f) {
    return (unsigned short)((__float_as_uint(f) + 0x8000u) >> 16);
}
__device__ __forceinline__ float bf2f(unsigned short h) {
    return __uint_as_float((unsigned)h << 16);
}
__device__ __forceinline__ void gl2lds16(const void* g, void* l) {
    __builtin_amdgcn_global_load_lds(
        (const __attribute__((address_space(1))) unsigned int*)g,
        (__attribute__((address_space(3))) unsigned int*)l, 16, 0, 0);
}

// ------- Kernel 1: GroupNorm statistics -------
__global__ __launch_bounds__(256) void gn_stats(const float* __restrict__ x,
                                                float* __restrict__ meanv,
                                                float* __restrict__ rstdv) {
    int bg = blockIdx.x;            // b*32 + g
    int b = bg >> 5, g = bg & 31;
    const float4* x4 = (const float4*)(x + (size_t)(b * CCH + g * 8) * NPIX);
    float s = 0.f, ss = 0.f;
    for (int e = threadIdx.x; e < 8 * NPIX / 4; e += 256) {
        float4 v = x4[e];
        s += v.x + v.y + v.z + v.w;
        ss += v.x * v.x + v.y * v.y + v.z * v.z + v.w * v.w;
    }
    __shared__ float rs[256], rss[256];
    rs[threadIdx.x] = s; rss[threadIdx.x] = ss;
    __syncthreads();
    for (int off = 128; off > 0; off >>= 1) {
        if (threadIdx.x < (unsigned)off) {
            rs[threadIdx.x] += rs[threadIdx.x + off];
            rss[threadIdx.x] += rss[threadIdx.x + off];
        }
        __syncthreads();
    }
    if (threadIdx.x == 0) {
        const float inv = 1.0f / (float)(8 * NPIX);
        float m = rs[0] * inv;
        float var = rss[0] * inv - m * m;
        meanv[bg] = m;
        rstdv[bg] = rsqrtf(var + EPS);
    }
}

// ------- Kernel 2: GN apply + transpose -> sb[n][c] bf16 -------
__global__ __launch_bounds__(256) void gn_tr(const float* __restrict__ x,
                                             const float* __restrict__ gamma,
                                             const float* __restrict__ beta,
                                             const float* __restrict__ meanv,
                                             const float* __restrict__ rstdv,
                                             unsigned short* __restrict__ sb) {
    __shared__ __align__(16) char lds[32768];   // [64 px][256 c] bf16, chunk-swizzled
    const int t = threadIdx.x;
    const int b = blockIdx.x >> 6, pt = blockIdx.x & 63;
    const int px = t & 63, cg = t >> 6;
    const float* xb = x + (((size_t)b * CCH) << 12) + pt * 64 + px;
#pragma unroll 8
    for (int cc = 0; cc < 64; ++cc) {
        int c = cc * 4 + cg;
        int bg = b * 32 + (c >> 3);
        float sc = rstdv[bg] * gamma[c];
        float sh = beta[c] - meanv[bg] * sc;
        float v = xb[(size_t)c << 12];           // coalesced along px
        *(unsigned short*)&lds[px * 512 + (((c >> 3) ^ (px & 31)) << 4) +
                               ((c & 7) << 1)] = f2bf(v * sc + sh);
    }
    __syncthreads();
    unsigned short* outp = sb + (((size_t)(b * NPIX + pt * 64)) << 8);
#pragma unroll
    for (int u = 0; u < 8; ++u) {
        int G = u * 256 + t;
        int prow = G >> 5, cc = G & 31;
        uint4 v = *(const uint4*)&lds[prow * 512 + ((cc ^ (prow & 31)) << 4)];
        *(uint4*)&outp[(size_t)G * 8] = v;
    }
}

// ------- Kernel 3: weights fp32 -> bf16 (order: p, q, k, v) -------
__global__ __launch_bounds__(256) void wcvt(const float* __restrict__ wq,
                                            const float* __restrict__ wk,
                                            const float* __restrict__ wv,
                                            const float* __restrict__ wp,
                                            unsigned short* __restrict__ wb) {
    int e = blockIdx.x * 256 + threadIdx.x;
    const float* srcs[4] = {wp, wq, wk, wv};
#pragma unroll
    for (int m = 0; m < 4; ++m) {
        float4 v = ((const float4*)srcs[m])[e];
        ushort4 h;
        h.x = f2bf(v.x); h.y = f2bf(v.y); h.z = f2bf(v.z); h.w = f2bf(v.w);
        *(ushort4*)(wb + (size_t)m * 65536 + (size_t)e * 4) = h;
    }
}

// ------- Kernel 4: QKV MFMA GEMM (unchanged, proven) -------
__global__ __launch_bounds__(256) void qkv_mfma(
    const unsigned short* __restrict__ sb, const unsigned short* __restrict__ wb,
    const float* __restrict__ bq, const float* __restrict__ bk,
    const float* __restrict__ bv,
    unsigned short* __restrict__ qT, unsigned short* __restrict__ kT,
    unsigned short* __restrict__ vB) {
    __shared__ __align__(16) char lds[34816];
    const int tid = threadIdx.x, lane = tid & 63, w = tid >> 6;
    const int ln15 = lane & 15, q = lane >> 4;
    const int n0 = blockIdx.x * 128;
    const int co0 = blockIdx.y * 128;
    const int z = blockIdx.z;
    const unsigned short* wm = wb + (size_t)(z + 1) * 65536;
    const float* bias = (z == 0) ? bq : (z == 1) ? bk : bv;

    f32x4 acc[2][8];
#pragma unroll
    for (int i2 = 0; i2 < 2; ++i2)
#pragma unroll
        for (int nf = 0; nf < 8; ++nf) {
            acc[i2][nf][0] = 0.f; acc[i2][nf][1] = 0.f;
            acc[i2][nf][2] = 0.f; acc[i2][nf][3] = 0.f;
        }

#pragma unroll 1
    for (int kt = 0; kt < 4; ++kt) {
#pragma unroll
        for (int r = 0; r < 4; ++r) {
            int gch = r * 256 + tid;
            int row = gch >> 3, sidx = gch & 7;
            int cc = sidx ^ (row & 7);
            gl2lds16(sb + ((size_t)(n0 + row) << 8) + kt * 64 + cc * 8,
                     &lds[r * 4096 + w * 1024]);
            gl2lds16(wm + ((size_t)(co0 + row) << 8) + kt * 64 + cc * 8,
                     &lds[16384 + r * 4096 + w * 1024]);
        }
        __syncthreads();
#pragma unroll
        for (int kk = 0; kk < 2; ++kk) {
            int kc = kk * 4 + q;
            bf16x8 af[2], bf[8];
#pragma unroll
            for (int i2 = 0; i2 < 2; ++i2) {
                int row = w * 32 + i2 * 16 + ln15;
                af[i2] = *(const bf16x8*)&lds[row * 128 + ((kc ^ (row & 7)) << 4)];
            }
#pragma unroll
            for (int nf = 0; nf < 8; ++nf) {
                int row = nf * 16 + ln15;
                bf[nf] = *(const bf16x8*)&lds[16384 + row * 128 + ((kc ^ (row & 7)) << 4)];
            }
#pragma unroll
            for (int i2 = 0; i2 < 2; ++i2)
#pragma unroll
                for (int nf = 0; nf < 8; ++nf)
                    acc[i2][nf] = __builtin_amdgcn_mfma_f32_16x16x32_bf16(
                        af[i2], bf[nf], acc[i2][nf], 0, 0, 0);
        }
        __syncthreads();
    }

    float bias_l[8];
#pragma unroll
    for (int nf = 0; nf < 8; ++nf) bias_l[nf] = bias[co0 + nf * 16 + ln15];
    const float scl = (z == 0) ? 0.0625f : 1.0f;   // C^-1/2 folded into q
    unsigned short* T = (unsigned short*)lds;
    if (z < 2) {
#pragma unroll
        for (int i2 = 0; i2 < 2; ++i2)
#pragma unroll
            for (int nf = 0; nf < 8; ++nf)
#pragma unroll
                for (int r = 0; r < 4; ++r) {
                    int n_l = w * 32 + i2 * 16 + q * 4 + r;
                    int co_l = nf * 16 + ln15;
                    T[n_l * 136 + co_l] = f2bf((acc[i2][nf][r] + bias_l[nf]) * scl);
                }
    } else {
#pragma unroll
        for (int i2 = 0; i2 < 2; ++i2)
#pragma unroll
            for (int nf = 0; nf < 8; ++nf)
#pragma unroll
                for (int r = 0; r < 4; ++r) {
                    int n_l = w * 32 + i2 * 16 + q * 4 + r;
                    int co_l = nf * 16 + ln15;
                    T[co_l * 136 + n_l] = f2bf(acc[i2][nf][r] + bias_l[nf]);
                }
    }
    __syncthreads();
    int row = tid >> 1, half = tid & 1;
    const uint4* src = (const uint4*)&T[row * 136 + half * 64];
    uint4* dst;
    if (z < 2) {
        unsigned short* qk = (z == 0) ? qT : kT;
        dst = (uint4*)(qk + ((size_t)(n0 + row) << 8) + co0 + half * 64);
    } else {
        int b2 = n0 >> 12, pix0 = n0 & 4095;
        dst = (uint4*)(vB + ((size_t)(b2 * CCH + co0 + row) << 12) + pix0 + half * 64);
    }
#pragma unroll
    for (int u = 0; u < 8; ++u) dst[u] = src[u];
}

// ------- Kernel 5: MFMA flash attention, double-buffered, 1 barrier/iter -------
// 512 threads = 8 waves = (ih 0..3: 32 i-rows each) x (jj 0..1: j-half).
// Block tile: 128 i x 2048 j (jh half); 32 iters of 64 j.
// LDS: buf0 [0,64K) = K 32K + V 32K; buf1 [64K,128K); P [128K,144K); lsum.
// stage(t+1) issued right after the single per-iter barrier -> a full compute
// phase to land before the next barrier's vmcnt drain (true overlap).
__global__ __launch_bounds__(512, 2) void attn_mfma(
    const unsigned short* __restrict__ qT, const unsigned short* __restrict__ kT,
    const unsigned short* __restrict__ vB,
    unsigned short* __restrict__ pO, float* __restrict__ pl) {
    __shared__ __align__(16) char lds[147968];
    const int tid = threadIdx.x, lane = tid & 63, w = tid >> 6;
    const int l5 = lane & 31, h = lane >> 5;
    const int ih = w >> 1, jj = w & 1;
    const int bx = blockIdx.x;
    const int jh = bx & 1, b = (bx >> 1) & 3, itile = bx >> 3;
    const int i0 = itile * 128;
    const size_t nb = (size_t)b * NPIX;
    const int wslot = 131072 + w * 2048;

    // ---- stage Q [128 i][256 c] into buf0 region, extract A-frags ----
#pragma unroll
    for (int t = 0; t < 8; ++t) {
        int gch = t * 512 + w * 64 + lane;
        int row = gch >> 5, sc = gch & 31;
        int cc = sc ^ (row & 7);
        gl2lds16(qT + ((nb + i0 + row) << 8) + cc * 8, &lds[t * 8192 + w * 1024]);
    }
    __syncthreads();
    bf16x8 qf[16];
    {
        int qrow = ih * 32 + l5;
#pragma unroll
        for (int kc = 0; kc < 16; ++kc)
            qf[kc] = *(const bf16x8*)&lds[qrow * 512 + (((kc * 2 + h) ^ (qrow & 7)) << 4)];
    }
    __syncthreads();

    // ---- preload tile 0 into buf0 ----
    {
        const int j0 = jh * 2048;
#pragma unroll
        for (int r = 0; r < 4; ++r) {
            int gch = r * 512 + w * 64 + lane;
            int row = gch >> 5, sc = gch & 31;
            int cc = sc ^ (row & 7);
            gl2lds16(kT + ((nb + j0 + row) << 8) + cc * 8, &lds[r * 8192 + w * 1024]);
            int c = gch >> 3, sv = gch & 7;
            int jc = sv ^ (c & 7);
            gl2lds16(vB + ((size_t)(b * CCH + c) << 12) + j0 + jc * 8,
                     &lds[32768 + r * 8192 + w * 1024]);
        }
    }

    f32x16 O[8];
#pragma unroll
    for (int ct = 0; ct < 8; ++ct)
#pragma unroll
        for (int r = 0; r < 16; ++r) O[ct][r] = 0.f;
    f32x16 l_acc;
#pragma unroll
    for (int r = 0; r < 16; ++r) l_acc[r] = 0.f;
    bf16x8 onesf;
#pragma unroll
    for (int e = 0; e < 8; ++e) onesf[e] = (short)0x3F80;   // bf16 1.0

#pragma unroll 1
    for (int jt = 0; jt < 32; ++jt) {
        __syncthreads();   // drains stage(jt); all reads of buf[(jt+1)&1] done
        // ---- issue stage(jt+1) into the other buffer (lands during compute) ----
        if (jt < 31) {
            const int j0 = jh * 2048 + (jt + 1) * 64;
            const int B = ((jt + 1) & 1) * 65536;
#pragma unroll
            for (int r = 0; r < 4; ++r) {
                int gch = r * 512 + w * 64 + lane;
                int row = gch >> 5, sc = gch & 31;
                int cc = sc ^ (row & 7);
                gl2lds16(kT + ((nb + j0 + row) << 8) + cc * 8,
                         &lds[B + r * 8192 + w * 1024]);
                int c = gch >> 3, sv = gch & 7;
                int jc = sv ^ (c & 7);
                gl2lds16(vB + ((size_t)(b * CCH + c) << 12) + j0 + jc * 8,
                         &lds[B + 32768 + r * 8192 + w * 1024]);
            }
        }
        const int B = (jt & 1) * 65536;

        // ---- scores S[32 i][32 j] ----
        f32x16 S;
#pragma unroll
        for (int r = 0; r < 16; ++r) S[r] = 0.f;
        {
            int krow = jj * 32 + l5;
#pragma unroll
            for (int kc = 0; kc < 16; ++kc) {
                bf16x8 kf = *(const bf16x8*)&lds[B + krow * 512 +
                                                 (((kc * 2 + h) ^ (krow & 7)) << 4)];
                S = __builtin_amdgcn_mfma_f32_32x32x16_bf16(qf[kc], kf, S, 0, 0, 0);
            }
        }

        // ---- P = exp(S) into private P region (no cross-wave hazard) ----
#pragma unroll
        for (int r = 0; r < 16; ++r) {
            int ir = (r & 3) + ((r >> 2) << 3) + (h << 2);
            float p = __expf(S[r]);
            *(unsigned short*)&lds[wslot + ir * 64 +
                (((l5 >> 3) ^ ((ir >> 1) & 3)) << 4) + ((l5 & 7) << 1)] = f2bf(p);
        }
        asm volatile("s_waitcnt lgkmcnt(0)" ::: "memory");

        bf16x8 pf0 = *(const bf16x8*)&lds[wslot + l5 * 64 + ((h ^ ((l5 >> 1) & 3)) << 4)];
        bf16x8 pf1 = *(const bf16x8*)&lds[wslot + l5 * 64 + (((2 + h) ^ ((l5 >> 1) & 3)) << 4)];

        l_acc = __builtin_amdgcn_mfma_f32_32x32x16_bf16(pf0, onesf, l_acc, 0, 0, 0);
        l_acc = __builtin_amdgcn_mfma_f32_32x32x16_bf16(pf1, onesf, l_acc, 0, 0, 0);

        // ---- PV ----
#pragma unroll
        for (int ct = 0; ct < 8; ++ct) {
            int cr = ct * 32 + l5;
            bf16x8 vf0 = *(const bf16x8*)&lds[B + 32768 + cr * 128 +
                                              (((jj * 4 + h) ^ (cr & 7)) << 4)];
            bf16x8 vf1 = *(const bf16x8*)&lds[B + 32768 + cr * 128 +
                                              (((jj * 4 + 2 + h) ^ (cr & 7)) << 4)];
            O[ct] = __builtin_amdgcn_mfma_f32_32x32x16_bf16(pf0, vf0, O[ct], 0, 0, 0);
            O[ct] = __builtin_amdgcn_mfma_f32_32x32x16_bf16(pf1, vf1, O[ct], 0, 0, 0);
        }
    }
    __syncthreads();   // all compute done; buffers dead

    // ---- epilogue: jj-merge through LDS, pl = l0+l1, coalesced pO dump ----
    if (jj == 1) {
#pragma unroll
        for (int ct = 0; ct < 8; ++ct)
#pragma unroll
            for (int r = 0; r < 16; ++r) {
                int ir = (r & 3) + ((r >> 2) << 3) + (h << 2);
                int i = ih * 32 + ir, c = ct * 32 + l5;
                *(unsigned short*)&lds[i * 512 + c * 2] = f2bf(O[ct][r]);
            }
        if (l5 == 0) {
#pragma unroll
            for (int r = 0; r < 16; ++r) {
                int ir = (r & 3) + ((r >> 2) << 3) + (h << 2);
                *(float*)&lds[147456 + (ih * 32 + ir) * 4] = l_acc[r];
            }
        }
    }
    __syncthreads();
    if (jj == 0) {
#pragma unroll
        for (int ct = 0; ct < 8; ++ct)
#pragma unroll
            for (int r = 0; r < 16; ++r) {
                int ir = (r & 3) + ((r >> 2) << 3) + (h << 2);
                int i = ih * 32 + ir, c = ct * 32 + l5;
                float v = O[ct][r] + bf2f(*(const unsigned short*)&lds[i * 512 + c * 2]);
                *(unsigned short*)&lds[i * 512 + c * 2] = f2bf(v);
            }
        if (l5 == 0) {
#pragma unroll
            for (int r = 0; r < 16; ++r) {
                int ir = (r & 3) + ((r >> 2) << 3) + (h << 2);
                int i = ih * 32 + ir;
                pl[bx * 128 + i] = l_acc[r] + *(const float*)&lds[147456 + i * 4];
            }
        }
    }
    __syncthreads();
#pragma unroll
    for (int u = 0; u < 8; ++u) {
        int G = u * 512 + tid;                   // 4096 16-B chunks, coalesced
        uint4 v = *(const uint4*)&lds[G * 16];
        *(uint4*)&pO[(size_t)bx * 32768 + (size_t)G * 8] = v;
    }
}

// ------- Kernel 6: proj GEMM with fused jh-merge + 1/l + bias + residual -------
__global__ __launch_bounds__(256) void proj_mfma(
    const unsigned short* __restrict__ pO, const float* __restrict__ pl,
    const unsigned short* __restrict__ wb, const float* __restrict__ bp,
    const float* __restrict__ x, float* __restrict__ out) {
    __shared__ __align__(16) char lds[34816];
    __shared__ float linv[128];
    const int tid = threadIdx.x, lane = tid & 63, w = tid >> 6;
    const int ln15 = lane & 15, q = lane >> 4;
    const int n0 = blockIdx.x * 128;
    const int co0 = blockIdx.y * 128;
    const int b2 = n0 >> 12, pix0 = n0 & 4095;

    if (tid < 128) {
        int pix = pix0 + tid;
        int bxA = (pix >> 7) * 8 + b2 * 2;       // jh=0 block; jh=1 at +1
        int il = pix & 127;
        float l = pl[bxA * 128 + il] + pl[(bxA + 1) * 128 + il];
        linv[tid] = 1.0f / l;
    }

    const int arow = tid >> 1, ah = tid & 1;
    const int pixr = pix0 + arow;
    const size_t srcA = (size_t)((pixr >> 7) * 8 + b2 * 2) * 32768 +
                        (size_t)(pixr & 127) * 256;

    f32x4 acc[2][8];
#pragma unroll
    for (int i2 = 0; i2 < 2; ++i2)
#pragma unroll
        for (int nf = 0; nf < 8; ++nf) {
            acc[i2][nf][0] = 0.f; acc[i2][nf][1] = 0.f;
            acc[i2][nf][2] = 0.f; acc[i2][nf][3] = 0.f;
        }
    __syncthreads();                             // linv ready

#pragma unroll 1
    for (int kt = 0; kt < 4; ++kt) {
#pragma unroll
        for (int r = 0; r < 4; ++r) {
            int gch = r * 256 + tid;
            int row = gch >> 3, sidx = gch & 7;
            int cc = sidx ^ (row & 7);
            gl2lds16(wb + ((size_t)(co0 + row) << 8) + kt * 64 + cc * 8,
                     &lds[16384 + r * 4096 + w * 1024]);
        }
        {
            float lin = linv[arow];
            int cbase = kt * 64 + ah * 32;
#pragma unroll
            for (int u = 0; u < 4; ++u) {
                uint4 a4 = *(const uint4*)&pO[srcA + cbase + u * 8];
                uint4 b4 = *(const uint4*)&pO[srcA + 32768 + cbase + u * 8];
                const unsigned short* as = (const unsigned short*)&a4;
                const unsigned short* bs = (const unsigned short*)&b4;
                __align__(16) unsigned short o8[8];
#pragma unroll
                for (int e = 0; e < 8; ++e)
                    o8[e] = f2bf((bf2f(as[e]) + bf2f(bs[e])) * lin);
                int cc = ah * 4 + u;
                *(uint4*)&lds[arow * 128 + ((cc ^ (arow & 7)) << 4)] = *(const uint4*)o8;
            }
        }
        __syncthreads();
#pragma unroll
        for (int kk = 0; kk < 2; ++kk) {
            int kc = kk * 4 + q;
            bf16x8 af[2], bf[8];
#pragma unroll
            for (int i2 = 0; i2 < 2; ++i2) {
                int row = w * 32 + i2 * 16 + ln15;
                af[i2] = *(const bf16x8*)&lds[row * 128 + ((kc ^ (row & 7)) << 4)];
            }
#pragma unroll
            for (int nf = 0; nf < 8; ++nf) {
                int row = nf * 16 + ln15;
                bf[nf] = *(const bf16x8*)&lds[16384 + row * 128 + ((kc ^ (row & 7)) << 4)];
            }
#pragma unroll
            for (int i2 = 0; i2 < 2; ++i2)
#pragma unroll
                for (int nf = 0; nf < 8; ++nf)
                    acc[i2][nf] = __builtin_amdgcn_mfma_f32_16x16x32_bf16(
                        af[i2], bf[nf], acc[i2][nf], 0, 0, 0);
        }
        __syncthreads();
    }

    unsigned short* T = (unsigned short*)lds;
#pragma unroll
    for (int i2 = 0; i2 < 2; ++i2)
#pragma unroll
        for (int nf = 0; nf < 8; ++nf)
#pragma unroll
            for (int r = 0; r < 4; ++r) {
                int n_l = w * 32 + i2 * 16 + q * 4 + r;
                int co_l = nf * 16 + ln15;
                T[co_l * 136 + n_l] = f2bf(acc[i2][nf][r]);
            }
    __syncthreads();
    int row = tid >> 1, half = tid & 1;          // row = co_local
    float br = bp[co0 + row];
    size_t gidx = (((size_t)(b2 * CCH + co0 + row)) << 12) + pix0 + half * 64;
    const unsigned short* trow = &T[row * 136 + half * 64];
#pragma unroll
    for (int u = 0; u < 16; ++u) {
        float4 xv = *(const float4*)&x[gidx + u * 4];
        ushort4 tv = *(const ushort4*)&trow[u * 4];
        float4 o;
        o.x = xv.x + br + bf2f(tv.x);
        o.y = xv.y + br + bf2f(tv.y);
        o.z = xv.z + br + bf2f(tv.z);
        o.w = xv.w + br + bf2f(tv.w);
        *(float4*)&out[gidx + u * 4] = o;
    }
}

extern "C" void kernel_launch(void* const* d_in, const int* in_sizes, int n_in,
                              void* d_out, int out_size, void* d_ws, size_t ws_size,
                              hipStream_t stream) {
    const float* x     = (const float*)d_in[0];
    const float* gamma = (const float*)d_in[1];
    const float* beta  = (const float*)d_in[2];
    const float* wq    = (const float*)d_in[3];
    const float* bq    = (const float*)d_in[4];
    const float* wk    = (const float*)d_in[5];
    const float* bk    = (const float*)d_in[6];
    const float* wv    = (const float*)d_in[7];
    const float* bv    = (const float*)d_in[8];
    const float* wp    = (const float*)d_in[9];
    const float* bp    = (const float*)d_in[10];
    float* out = (float*)d_out;

    char* wsb = (char*)d_ws;
    float*          meanv = (float*)(wsb + 51200000);              // 512 B
    float*          rstdv = (float*)(wsb + 51201024);              // 512 B
    unsigned short* sb = (unsigned short*)wsb;                     //  8 MB
    unsigned short* wb = (unsigned short*)(wsb + 8388608);         // 512 KB
    unsigned short* qT = (unsigned short*)(wsb + 8912896);         //  8 MB
    unsigned short* kT = (unsigned short*)(wsb + 17301504);        //  8 MB
    unsigned short* vB = (unsigned short*)(wsb + 25690112);        //  8 MB
    unsigned short* pO = (unsigned short*)(wsb + 34078720);        // 16 MB
    float*          pl = (float*)(wsb + 50855936);                 // 128 KB

    gn_stats<<<BB * 32, 256, 0, stream>>>(x, meanv, rstdv);
    gn_tr<<<BB * 64, 256, 0, stream>>>(x, gamma, beta, meanv, rstdv, sb);
    wcvt<<<64, 256, 0, stream>>>(wq, wk, wv, wp, wb);
    qkv_mfma<<<dim3(128, 2, 3), 256, 0, stream>>>(sb, wb, bq, bk, bv, qT, kT, vB);
    attn_mfma<<<256, 512, 0, stream>>>(qT, kT, vB, pO, pl);
    proj_mfma<<<dim3(128, 2), 256, 0, stream>>>(pO, pl, wb, bp, x, out);
}